// Round 1
// baseline (117.857 us; speedup 1.0000x reference)
//
#include <hip/hip_runtime.h>
#include <hip/hip_bf16.h>

// MIoU (buggy-source-faithful): result = popcount(classes 1..20 present in y_pred) / 21.
// y_true is dead in the reference. Presence scan over 64 MiB of int32.
//
// R1: same-address atomicOr serialized (~31 cyc/op) -> 107 us scan.
// R2: atomic-free -> total 134 us; scan ~22 us (3.2 TB/s read).
// R3: flat 4-load neutral -> not load-issue-bound.
// R4: wave-contiguous single-pass neutral -> memory-path ceiling.
// R6: nt loads WIN (-4 us): part of the cap was L2-allocate churn.
// R7: algorithmic short-circuit (probe 64 KB prefix; scan/finalize early-exit
//   on flag) -> 118 us. rocprof now shows top-5 dispatches are ALL harness
//   fillBufferAligned (256 MiB poison @ ~6.3-6.6 TB/s = HBM write ceiling);
//   our kernels are single-digit us.
// R8 (this round): shrink the controllable remainder. Fold finalize into the
//   scan via last-block-done (atomicOr accumulator + device-scope counter;
//   only executes on the never-taken fallback path), cut scan grid 2048->1024
//   to halve the early-exit dispatch drain. 3 launches -> 2.

#define NUM_CLASSES 21
#define FULL_MASK 0x001FFFFEu   // bits 1..20
#define SCAN_GRID 1024
#define SCAN_BLOCK 256
#define WAVES_PER_BLOCK (SCAN_BLOCK / 64)
#define PROBE_INTS 16384        // 64 KB prefix; P(class missing) ~ 1e-338

typedef int vint4 __attribute__((ext_vector_type(4)));

__device__ __forceinline__ unsigned int block_or_reduce(unsigned int m,
                                                        unsigned int* wmask) {
    #pragma unroll
    for (int off = 32; off >= 1; off >>= 1) {
        m |= __shfl_xor(m, off, 64);
    }
    if ((threadIdx.x & 63) == 0) {
        wmask[threadIdx.x >> 6] = m;
    }
    __syncthreads();
    return wmask[0] | wmask[1] | wmask[2] | wmask[3];
}

// Probe: scan the first 64 KB. If classes 1..20 all present (certain for the
// bench's uniform-random input), write the answer and set the flag so the scan
// kernel early-exits. Also re-zeros the fallback accumulator/counter each
// iteration (workspace is poisoned by the harness between iterations).
__global__ __launch_bounds__(256) void miou_probe(
        const int* __restrict__ yp, int n,
        unsigned int* __restrict__ flag,
        unsigned int* __restrict__ acc,   // acc[0]=mask OR, acc[1]=done count
        float* __restrict__ out) {
    const vint4* __restrict__ yp4 = (const vint4*)yp;
    unsigned int m = 0u;
    if (n >= PROBE_INTS) {
        const int t = threadIdx.x;
        #pragma unroll
        for (int k = 0; k < PROBE_INTS / (4 * 256); ++k) {
            vint4 v = yp4[t + k * 256];
            m |= (1u << v.x) | (1u << v.y) | (1u << v.z) | (1u << v.w);
        }
    }
    __shared__ unsigned int wmask[4];
    unsigned int all = block_or_reduce(m, wmask);
    if (threadIdx.x == 0) {
        acc[0] = 0u;            // reset fallback accumulator (ws is poisoned)
        acc[1] = 0u;            // reset done-counter
        if ((all & FULL_MASK) == FULL_MASK) {
            out[0] = (float)__popc(FULL_MASK) / (float)NUM_CLASSES;
            *flag = 1u;
        } else {
            *flag = 0u;
        }
    }
}

// Fused scan + finalize. Early-exits on the probe flag (the benched path:
// every block loads one dword and retires). Fallback path is exact for any
// input: grid-stride nt-load scan, one atomicOr per block, last-block-done
// writes the answer. Fallback perf is correctness insurance only.
__global__ __launch_bounds__(SCAN_BLOCK) void miou_scan(
        const int* __restrict__ yp,
        const unsigned int* __restrict__ flag,
        unsigned int* __restrict__ acc,
        float* __restrict__ out,
        int n4) {
    if (*flag) return;   // answer already decided by the probe

    const vint4* __restrict__ yp4 = (const vint4*)yp;
    unsigned int m = 0u;
    const int idx = blockIdx.x * blockDim.x + threadIdx.x;
    const int stride = gridDim.x * blockDim.x;
    for (int i = idx; i < n4; i += stride) {
        vint4 v = __builtin_nontemporal_load(yp4 + i);
        m |= (1u << v.x) | (1u << v.y) | (1u << v.z) | (1u << v.w);
    }

    __shared__ unsigned int wmask[WAVES_PER_BLOCK];
    unsigned int all = block_or_reduce(m, wmask);
    if (threadIdx.x == 0) {
        // Device-scope atomics (default on CDNA4) give cross-XCD coherence.
        atomicOr(&acc[0], all);
        __threadfence();                       // release: OR visible before count
        unsigned int prev = atomicAdd(&acc[1], 1u);
        if (prev == gridDim.x - 1) {
            __threadfence();                   // acquire before final read
            unsigned int final_mask = atomicOr(&acc[0], 0u);  // coherent read
            out[0] = (float)__popc(final_mask & FULL_MASK) / (float)NUM_CLASSES;
        }
    }
}

extern "C" void kernel_launch(void* const* d_in, const int* in_sizes, int n_in,
                              void* d_out, int out_size, void* d_ws, size_t ws_size,
                              hipStream_t stream) {
    const int* y_pred = (const int*)d_in[0];
    // d_in[1] (y_true) is dead in the reference.
    float* out = (float*)d_out;
    unsigned int* flag = (unsigned int*)d_ws;              // ws[0]
    unsigned int* acc  = (unsigned int*)d_ws + 16;         // ws[16..17], own line

    int n = in_sizes[0];   // 16,777,216
    int n4 = n >> 2;

    miou_probe<<<1, 256, 0, stream>>>(y_pred, n, flag, acc, out);
    miou_scan<<<SCAN_GRID, SCAN_BLOCK, 0, stream>>>(y_pred, flag, acc, out, n4);
}